// Round 14
// baseline (186.427 us; speedup 1.0000x reference)
//
#include <hip/hip_runtime.h>

// R14: ABLATION round. V0 = exact R10 kernel (verified: absmax 4, 44.2us).
// P1 = loads+gathers only, 3 reps. P2 = loads+DS writes+frag reads (no MFMA),
// 2 reps. Decode: L = P1/3; W+R = P2/2 - L; MFMA+resid = V0 - P2/2.
// Probes write to scratch; V0 feeds the real reduction. asm volatile keeps
// ablated values live (guide rule #17: ablation-via-skip DCEs upstream ops).

#define NG 64
#define NCOMP 6
#define NPART (NG * NCOMP)      // 384
#define RED1_BLOCKS 64
#define MFMA_BLOCKS 768         // 3 blocks/CU
#define WPB 4
#define MROW 72                 // 64 + 8 pad ushorts; 144B rows (16B-aligned)
#define DROW 72

typedef unsigned short u16_t;
typedef unsigned int   u32_t;
typedef __attribute__((ext_vector_type(8))) short short8;
typedef __attribute__((ext_vector_type(4))) float f32x4;

__device__ __forceinline__ u16_t f2bf(float f) {
    union { float f; u32_t u; } v; v.f = f;
    u32_t r = v.u + 0x7FFFu + ((v.u >> 16) & 1u);
    return (u16_t)(r >> 16);
}

__device__ __forceinline__ void lds_add(float* p, float v) {
    __hip_atomic_fetch_add(p, v, __ATOMIC_RELAXED, __HIP_MEMORY_SCOPE_WORKGROUP);
}

__device__ __forceinline__ void keep4(short8 v) {
    f32x4 t = __builtin_bit_cast(f32x4, v);
    asm volatile("" :: "v"(t[0]), "v"(t[1]), "v"(t[2]), "v"(t[3]));
}

// V: 0 = full (R10-identical), 1 = loads+writes+reads (no MFMA), 3 = loads only
template<int V, int REPS>
__global__ __launch_bounds__(256) void virial_abl(
    const float* __restrict__ disp, const float* __restrict__ edge_w,
    const int* __restrict__ edge_index, const int* __restrict__ batch,
    float* __restrict__ partials, int E)
{
    __shared__ u16_t Msh[WPB][NG * MROW];   // 36864 B
    __shared__ u16_t Dsh[WPB][16 * DROW];   //  9216 B (V0: reused as f32 stage)

    const int lane = threadIdx.x & 63;
    const int wave = threadIdx.x >> 6;
    u16_t* Mw = Msh[wave];
    u16_t* Dw = Dsh[wave];

    {   // zero per-wave M and Dt (same-wave DS ops are in order; no barrier)
        u32_t* p = (u32_t*)Mw;
        for (int i = lane; i < NG * MROW / 2; i += 64) p[i] = 0u;
        u32_t* q = (u32_t*)Dw;
        for (int i = lane; i < 16 * DROW / 2; i += 64) q[i] = 0u;
    }

    f32x4 acc0 = {0,0,0,0}, acc1 = {0,0,0,0}, acc2 = {0,0,0,0}, acc3 = {0,0,0,0};
    const int ngroups = (E + 63) >> 6;
    const int gstride = (int)gridDim.x * WPB;
    const int c_l = lane & 15;
    const int k4  = lane >> 4;
    int pg0 = 0, pg1 = 0;

    for (int rep = 0; rep < REPS; ++rep) {
        int grp = (int)blockIdx.x * WPB + wave;

        // ---- 1-deep prefetch of the load chain (plain code) ----
        int   p_g0 = 0, p_g1 = 0;
        float p_w = 0.f, p_d0 = 0.f, p_d1 = 0.f, p_d2 = 0.f;
        if (grp < ngroups) {
            int e  = grp * 64 + lane;
            int ec = e < E ? e : E - 1;
            p_w  = (e < E) ? edge_w[ec] : 0.f;
            p_d0 = disp[ec * 3 + 0];
            p_d1 = disp[ec * 3 + 1];
            p_d2 = disp[ec * 3 + 2];
            p_g0 = batch[edge_index[ec]];
            p_g1 = batch[edge_index[E + ec]];
        }

        while (grp < ngroups) {
            const int   g0 = p_g0, g1 = p_g1;
            const float w = p_w, d0 = p_d0, d1 = p_d1, d2 = p_d2;

            const int nxt = grp + gstride;
            if (nxt < ngroups) {
                int e  = nxt * 64 + lane;
                int ec = e < E ? e : E - 1;
                p_w  = (e < E) ? edge_w[ec] : 0.f;
                p_d0 = disp[ec * 3 + 0];
                p_d1 = disp[ec * 3 + 1];
                p_d2 = disp[ec * 3 + 2];
                p_g0 = batch[edge_index[ec]];
                p_g1 = batch[edge_index[E + ec]];
            }

            if constexpr (V == 3) {
                // loads only: keep everything live, no DS/MFMA
                asm volatile("" :: "v"(w), "v"(d0), "v"(d1), "v"(d2),
                                   "v"(g0), "v"(g1));
            } else {
                // M one-hot (lane = column; plain stores; zero stale rows)
                Mw[pg0 * MROW + lane] = 0;
                Mw[pg1 * MROW + lane] = 0;
                Mw[g0 * MROW + lane] = 0x3F80u;                          // 1.0
                Mw[g1 * MROW + lane] = (g1 == g0) ? 0x4000u : 0x3F80u;   // 2.0/1.0
                pg0 = g0; pg1 = g1;

                float cw = -2.f * w;
                Dw[0 * DROW + lane] = f2bf(cw * d0 * d0);
                Dw[1 * DROW + lane] = f2bf(cw * d0 * d1);
                Dw[2 * DROW + lane] = f2bf(cw * d0 * d2);
                Dw[3 * DROW + lane] = f2bf(cw * d1 * d1);
                Dw[4 * DROW + lane] = f2bf(cw * d1 * d2);
                Dw[5 * DROW + lane] = f2bf(cw * d2 * d2);

#pragma unroll
                for (int half = 0; half < 2; ++half) {
                    const int kb = half * 32 + k4 * 8;
                    short8 bf = *(const short8*)&Dw[c_l * DROW + kb];
                    short8 a0 = *(const short8*)&Mw[( 0 + c_l) * MROW + kb];
                    short8 a1 = *(const short8*)&Mw[(16 + c_l) * MROW + kb];
                    short8 a2 = *(const short8*)&Mw[(32 + c_l) * MROW + kb];
                    short8 a3 = *(const short8*)&Mw[(48 + c_l) * MROW + kb];
                    if constexpr (V == 1) {
                        keep4(bf); keep4(a0); keep4(a1); keep4(a2); keep4(a3);
                    } else {
                        acc0 = __builtin_amdgcn_mfma_f32_16x16x32_bf16(a0, bf, acc0, 0, 0, 0);
                        acc1 = __builtin_amdgcn_mfma_f32_16x16x32_bf16(a1, bf, acc1, 0, 0, 0);
                        acc2 = __builtin_amdgcn_mfma_f32_16x16x32_bf16(a2, bf, acc2, 0, 0, 0);
                        acc3 = __builtin_amdgcn_mfma_f32_16x16x32_bf16(a3, bf, acc3, 0, 0, 0);
                    }
                }
            }

            grp = nxt;
        }
    }

    if constexpr (V == 0) {
        // C/D layout: col=lane&15, row=(lane>>4)*4+reg (m89-verified)
        float* Ow = (float*)Dw;   // Dt dead; 2304 B >= 1536 B needed
        if (c_l < NCOMP) {
#pragma unroll
            for (int r = 0; r < 4; ++r) {
                Ow[( 0 + k4 * 4 + r) * NCOMP + c_l] = acc0[r];
                Ow[(16 + k4 * 4 + r) * NCOMP + c_l] = acc1[r];
                Ow[(32 + k4 * 4 + r) * NCOMP + c_l] = acc2[r];
                Ow[(48 + k4 * 4 + r) * NCOMP + c_l] = acc3[r];
            }
        }
        __syncthreads();
        for (int i = threadIdx.x; i < NPART; i += blockDim.x) {
            float s = ((const float*)Dsh[0])[i] + ((const float*)Dsh[1])[i]
                    + ((const float*)Dsh[2])[i] + ((const float*)Dsh[3])[i];
            partials[(size_t)blockIdx.x * NPART + i] = s;
        }
    } else {
        // probes: scratch write only (asm keeps did the real work)
        if (threadIdx.x == 0)
            partials[(size_t)blockIdx.x * NPART] = 0.f;
    }
}

// ---------------- reductions (atomic-free) ----------------
__global__ __launch_bounds__(NPART) void reduce1_kernel(
    const float* __restrict__ partials, float* __restrict__ partials2, int nblk)
{
    int i = threadIdx.x, j = blockIdx.x;
    float s = 0.f;
    for (int b = j; b < nblk; b += RED1_BLOCKS)
        s += partials[(size_t)b * NPART + i];
    partials2[(size_t)j * NPART + i] = s;
}

__global__ __launch_bounds__(NPART) void reduce2_kernel(
    const float* __restrict__ partials2, float* __restrict__ dst)  // dst: 64*9
{
    int i = threadIdx.x;
    float s = 0.f;
#pragma unroll
    for (int j = 0; j < RED1_BLOCKS; ++j)
        s += partials2[(size_t)j * NPART + i];
    int g = i / NCOMP, c = i % NCOMP;
    int r   = (c < 3) ? 0 : ((c < 5) ? 1 : 2);
    int col = (c < 3) ? c : ((c < 5) ? c - 2 : 2);
    dst[g * 9 + r * 3 + col] = s;
    if (r != col) dst[g * 9 + col * 3 + r] = s;
}

// ---------------- fallback (tiny ws): LDS-atomic path ----------------
__global__ void zero_out_kernel(float* __restrict__ out, int n) {
    int i = blockIdx.x * blockDim.x + threadIdx.x;
    if (i < n) out[i] = 0.f;
}

__global__ __launch_bounds__(256) void virial_atomic(
    const float* __restrict__ disp, const float* __restrict__ edge_w,
    const int* __restrict__ edge_index, const int* __restrict__ batch,
    float* __restrict__ out, int E)
{
    __shared__ float acc[NG * 7];
    for (int i = threadIdx.x; i < NG * 7; i += blockDim.x) acc[i] = 0.f;
    __syncthreads();
    int tid = blockIdx.x * blockDim.x + threadIdx.x;
    int stride = gridDim.x * blockDim.x;
    for (int e = tid; e < E; e += stride) {
        float d0 = disp[e*3], d1 = disp[e*3+1], d2 = disp[e*3+2];
        float c = -2.f * edge_w[e];
        int g0 = batch[edge_index[e]], g1 = batch[edge_index[E + e]];
        float v[6] = {c*d0*d0, c*d0*d1, c*d0*d2, c*d1*d1, c*d1*d2, c*d2*d2};
#pragma unroll
        for (int k = 0; k < 6; ++k) {
            lds_add(&acc[g0*7+k], v[k]);
            lds_add(&acc[g1*7+k], v[k]);
        }
    }
    __syncthreads();
    for (int i = threadIdx.x; i < NG * 9; i += blockDim.x) {
        int g = i / 9, ij = i % 9, r = ij / 3, cc = ij % 3;
        int lo = r < cc ? r : cc, hi = r < cc ? cc : r;
        int comp = (lo == 0) ? hi : ((lo == 1) ? 2 + hi : 5);
        __hip_atomic_fetch_add(&out[i], acc[g*7+comp], __ATOMIC_RELAXED, __HIP_MEMORY_SCOPE_AGENT);
    }
}

extern "C" void kernel_launch(void* const* d_in, const int* in_sizes, int n_in,
                              void* d_out, int out_size, void* d_ws, size_t ws_size,
                              hipStream_t stream) {
    const float* disp       = (const float*)d_in[0];
    const float* edge_w     = (const float*)d_in[1];
    const int*   edge_index = (const int*)d_in[2];
    const int*   batch      = (const int*)d_in[3];
    float*       out        = (float*)d_out;
    const int E = in_sizes[1];

    // pm (768) + p2 (64) + scratch (768), all NPART floats each
    const size_t need = (size_t)(2 * MFMA_BLOCKS + RED1_BLOCKS) * NPART * sizeof(float);

    if (ws_size >= need) {
        float* pm      = (float*)d_ws;
        float* p2      = pm + (size_t)MFMA_BLOCKS * NPART;
        float* scratch = p2 + (size_t)RED1_BLOCKS * NPART;

        // Probes first (results discarded), then the real kernel + reduction.
        virial_abl<3, 3><<<MFMA_BLOCKS, 256, 0, stream>>>(disp, edge_w, edge_index, batch, scratch, E);
        virial_abl<1, 2><<<MFMA_BLOCKS, 256, 0, stream>>>(disp, edge_w, edge_index, batch, scratch, E);
        virial_abl<0, 1><<<MFMA_BLOCKS, 256, 0, stream>>>(disp, edge_w, edge_index, batch, pm, E);
        reduce1_kernel<<<RED1_BLOCKS, NPART, 0, stream>>>(pm, p2, MFMA_BLOCKS);
        reduce2_kernel<<<1, NPART, 0, stream>>>(p2, out);
    } else {
        zero_out_kernel<<<1, 256, 0, stream>>>(out, NG * 9);
        virial_atomic<<<2048, 256, 0, stream>>>(disp, edge_w, edge_index, batch, out, E);
    }
}

// Round 15
// 53.667 us; speedup vs baseline: 3.4737x; 3.4737x over previous
//
#include <hip/hip_runtime.h>

// R15: vectorized macro-loads. R14 ablation: loads+gathers alone = 31.7us of
// V0's 44.2 (latency/issue-bound: 24 narrow VMEM/256 edges, 1-deep chain).
// Now: per wave, 256-edge macro-iteration -> 6x dwordx4 streaming loads +
// 8 batched independent gathers (14 wide VMEM instrs), 1-deep macro prefetch.
// Per 64-edge phase, a shfl redistribution (reg idx = lane&3 const) hands
// lane l edge l's data; M/Dt/MFMA body stays BYTE-IDENTICAL to the
// twice-verified R10 kernel (absmax 4).

#define NG 64
#define NCOMP 6
#define NPART (NG * NCOMP)      // 384
#define RED1_BLOCKS 64
#define MFMA_BLOCKS 768         // 3 blocks/CU (LDS-capped)
#define WPB 4
#define MROW 72                 // 64 + 8 pad ushorts; 144B rows (16B-aligned)
#define DROW 72

typedef unsigned short u16_t;
typedef unsigned int   u32_t;
typedef __attribute__((ext_vector_type(8))) short short8;
typedef __attribute__((ext_vector_type(4))) float f32x4;

__device__ __forceinline__ u16_t f2bf(float f) {
    union { float f; u32_t u; } v; v.f = f;
    u32_t r = v.u + 0x7FFFu + ((v.u >> 16) & 1u);
    return (u16_t)(r >> 16);
}

__device__ __forceinline__ float sel4f(float a, float b, float c, float d, int k) {
    float ab = (k & 1) ? b : a;
    float cd = (k & 1) ? d : c;
    return (k & 2) ? cd : ab;
}
__device__ __forceinline__ int sel4i(int a, int b, int c, int d, int k) {
    int ab = (k & 1) ? b : a;
    int cd = (k & 1) ? d : c;
    return (k & 2) ? cd : ab;
}

__device__ __forceinline__ void lds_add(float* p, float v) {
    __hip_atomic_fetch_add(p, v, __ATOMIC_RELAXED, __HIP_MEMORY_SCOPE_WORKGROUP);
}

// Load one 256-edge macro: lane holds 4 consecutive edges (eb = mac*256+4*lane).
// Vector path when the whole macro is in range; scalar clamped path for tail.
#define LOADQ(MAC, W, X, Y, Z, GP) do {                                        \
    int eb_ = (MAC) * 256 + 4 * lane;                                          \
    if (((MAC) + 1) * 256 <= E) {                                              \
        float4 w4_ = *(const float4*)&edge_w[eb_];                             \
        float4 dA_ = *(const float4*)&disp[eb_ * 3 + 0];                       \
        float4 dB_ = *(const float4*)&disp[eb_ * 3 + 4];                       \
        float4 dC_ = *(const float4*)&disp[eb_ * 3 + 8];                       \
        int4   s4_ = *(const int4*)&edge_index[eb_];                           \
        int4   t4_ = *(const int4*)&edge_index[E + eb_];                       \
        W[0] = w4_.x; W[1] = w4_.y; W[2] = w4_.z; W[3] = w4_.w;                \
        X[0] = dA_.x; Y[0] = dA_.y; Z[0] = dA_.z;                              \
        X[1] = dA_.w; Y[1] = dB_.x; Z[1] = dB_.y;                              \
        X[2] = dB_.z; Y[2] = dB_.w; Z[2] = dC_.x;                              \
        X[3] = dC_.y; Y[3] = dC_.z; Z[3] = dC_.w;                              \
        GP[0] = batch[s4_.x] | (batch[t4_.x] << 8);                            \
        GP[1] = batch[s4_.y] | (batch[t4_.y] << 8);                            \
        GP[2] = batch[s4_.z] | (batch[t4_.z] << 8);                            \
        GP[3] = batch[s4_.w] | (batch[t4_.w] << 8);                            \
    } else {                                                                   \
        _Pragma("unroll")                                                      \
        for (int k_ = 0; k_ < 4; ++k_) {                                       \
            int e_  = eb_ + k_;                                                \
            int ec_ = e_ < E ? e_ : E - 1;                                     \
            W[k_] = (e_ < E) ? edge_w[ec_] : 0.f;                              \
            X[k_] = disp[ec_ * 3 + 0];                                         \
            Y[k_] = disp[ec_ * 3 + 1];                                         \
            Z[k_] = disp[ec_ * 3 + 2];                                         \
            GP[k_] = batch[edge_index[ec_]] | (batch[edge_index[E + ec_]] << 8);\
        }                                                                      \
    }                                                                          \
} while (0)

// ---------------- MFMA main kernel ----------------
__global__ __launch_bounds__(256) void virial_mfma(
    const float* __restrict__ disp, const float* __restrict__ edge_w,
    const int* __restrict__ edge_index, const int* __restrict__ batch,
    float* __restrict__ partials, int E)
{
    __shared__ u16_t Msh[WPB][NG * MROW];   // 36864 B
    __shared__ u16_t Dsh[WPB][16 * DROW];   //  9216 B (rows 6..15 stay zero;
                                            //  reused as per-wave f32 stage)
    const int lane = threadIdx.x & 63;
    const int wave = threadIdx.x >> 6;
    u16_t* Mw = Msh[wave];
    u16_t* Dw = Dsh[wave];

    {   // zero per-wave M and Dt (same-wave DS ops are in order; no barrier)
        u32_t* p = (u32_t*)Mw;
        for (int i = lane; i < NG * MROW / 2; i += 64) p[i] = 0u;
        u32_t* q = (u32_t*)Dw;
        for (int i = lane; i < 16 * DROW / 2; i += 64) q[i] = 0u;
    }

    f32x4 acc0 = {0,0,0,0}, acc1 = {0,0,0,0}, acc2 = {0,0,0,0}, acc3 = {0,0,0,0};
    const int nmacros = (E + 255) >> 8;
    const int mstride = (int)gridDim.x * WPB;
    const int c_l = lane & 15;
    const int k4  = lane >> 4;
    const int ksel = lane & 3;
    int pg0 = 0, pg1 = 0;

    int mac = (int)blockIdx.x * WPB + wave;

    // 1-deep macro prefetch
    float nw[4] = {0,0,0,0}, nx[4] = {0,0,0,0}, ny[4] = {0,0,0,0}, nz[4] = {0,0,0,0};
    int   ngp[4] = {0,0,0,0};
    if (mac < nmacros) LOADQ(mac, nw, nx, ny, nz, ngp);

    while (mac < nmacros) {
        float aw[4], ax[4], ay[4], az[4];
        int   agp[4];
#pragma unroll
        for (int k = 0; k < 4; ++k) {
            aw[k] = nw[k]; ax[k] = nx[k]; ay[k] = ny[k]; az[k] = nz[k];
            agp[k] = ngp[k];
        }
        const int nxt = mac + mstride;
        if (nxt < nmacros) LOADQ(nxt, nw, nx, ny, nz, ngp);   // in flight during phases

#pragma unroll
        for (int j = 0; j < 4; ++j) {
            // redistribute: lane <- data of within-group edge 'lane' of sub-group j
            const int src = 16 * j + (lane >> 2);
            float wv = sel4f(__shfl(aw[0], src), __shfl(aw[1], src),
                             __shfl(aw[2], src), __shfl(aw[3], src), ksel);
            float xv = sel4f(__shfl(ax[0], src), __shfl(ax[1], src),
                             __shfl(ax[2], src), __shfl(ax[3], src), ksel);
            float yv = sel4f(__shfl(ay[0], src), __shfl(ay[1], src),
                             __shfl(ay[2], src), __shfl(ay[3], src), ksel);
            float zv = sel4f(__shfl(az[0], src), __shfl(az[1], src),
                             __shfl(az[2], src), __shfl(az[3], src), ksel);
            int  gpv = sel4i(__shfl(agp[0], src), __shfl(agp[1], src),
                             __shfl(agp[2], src), __shfl(agp[3], src), ksel);
            const int g0 = gpv & 0xFF;
            const int g1 = (gpv >> 8) & 0xFF;

            // --- R10-verified body: M one-hot (column = lane), Dt, 8 MFMA ---
            Mw[pg0 * MROW + lane] = 0;
            Mw[pg1 * MROW + lane] = 0;
            Mw[g0 * MROW + lane] = 0x3F80u;                          // 1.0
            Mw[g1 * MROW + lane] = (g1 == g0) ? 0x4000u : 0x3F80u;   // 2.0 / 1.0
            pg0 = g0; pg1 = g1;

            float cwv = -2.f * wv;
            Dw[0 * DROW + lane] = f2bf(cwv * xv * xv);
            Dw[1 * DROW + lane] = f2bf(cwv * xv * yv);
            Dw[2 * DROW + lane] = f2bf(cwv * xv * zv);
            Dw[3 * DROW + lane] = f2bf(cwv * yv * yv);
            Dw[4 * DROW + lane] = f2bf(cwv * yv * zv);
            Dw[5 * DROW + lane] = f2bf(cwv * zv * zv);

#pragma unroll
            for (int half = 0; half < 2; ++half) {
                const int kb = half * 32 + k4 * 8;
                short8 bf = *(const short8*)&Dw[c_l * DROW + kb];
                short8 a0 = *(const short8*)&Mw[( 0 + c_l) * MROW + kb];
                short8 a1 = *(const short8*)&Mw[(16 + c_l) * MROW + kb];
                short8 a2 = *(const short8*)&Mw[(32 + c_l) * MROW + kb];
                short8 a3 = *(const short8*)&Mw[(48 + c_l) * MROW + kb];
                acc0 = __builtin_amdgcn_mfma_f32_16x16x32_bf16(a0, bf, acc0, 0, 0, 0);
                acc1 = __builtin_amdgcn_mfma_f32_16x16x32_bf16(a1, bf, acc1, 0, 0, 0);
                acc2 = __builtin_amdgcn_mfma_f32_16x16x32_bf16(a2, bf, acc2, 0, 0, 0);
                acc3 = __builtin_amdgcn_mfma_f32_16x16x32_bf16(a3, bf, acc3, 0, 0, 0);
            }
        }

        mac = nxt;
    }

    // C/D layout: col=lane&15, row=(lane>>4)*4+reg (m89-verified)
    float* Ow = (float*)Dw;   // Dt dead; 2304 B >= 1536 B needed
    if (c_l < NCOMP) {
#pragma unroll
        for (int r = 0; r < 4; ++r) {
            Ow[( 0 + k4 * 4 + r) * NCOMP + c_l] = acc0[r];
            Ow[(16 + k4 * 4 + r) * NCOMP + c_l] = acc1[r];
            Ow[(32 + k4 * 4 + r) * NCOMP + c_l] = acc2[r];
            Ow[(48 + k4 * 4 + r) * NCOMP + c_l] = acc3[r];
        }
    }
    __syncthreads();
    for (int i = threadIdx.x; i < NPART; i += blockDim.x) {
        float s = ((const float*)Dsh[0])[i] + ((const float*)Dsh[1])[i]
                + ((const float*)Dsh[2])[i] + ((const float*)Dsh[3])[i];
        partials[(size_t)blockIdx.x * NPART + i] = s;
    }
}

// ---------------- reductions (atomic-free) ----------------
__global__ __launch_bounds__(NPART) void reduce1_kernel(
    const float* __restrict__ partials, float* __restrict__ partials2, int nblk)
{
    int i = threadIdx.x, j = blockIdx.x;
    float s = 0.f;
    for (int b = j; b < nblk; b += RED1_BLOCKS)
        s += partials[(size_t)b * NPART + i];
    partials2[(size_t)j * NPART + i] = s;
}

__global__ __launch_bounds__(NPART) void reduce2_kernel(
    const float* __restrict__ partials2, float* __restrict__ dst)  // dst: 64*9
{
    int i = threadIdx.x;
    float s = 0.f;
#pragma unroll
    for (int j = 0; j < RED1_BLOCKS; ++j)
        s += partials2[(size_t)j * NPART + i];
    int g = i / NCOMP, c = i % NCOMP;
    int r   = (c < 3) ? 0 : ((c < 5) ? 1 : 2);
    int col = (c < 3) ? c : ((c < 5) ? c - 2 : 2);
    dst[g * 9 + r * 3 + col] = s;
    if (r != col) dst[g * 9 + col * 3 + r] = s;
}

// ---------------- fallback (tiny ws): LDS-atomic path ----------------
__global__ void zero_out_kernel(float* __restrict__ out, int n) {
    int i = blockIdx.x * blockDim.x + threadIdx.x;
    if (i < n) out[i] = 0.f;
}

__global__ __launch_bounds__(256) void virial_atomic(
    const float* __restrict__ disp, const float* __restrict__ edge_w,
    const int* __restrict__ edge_index, const int* __restrict__ batch,
    float* __restrict__ out, int E)
{
    __shared__ float acc[NG * 7];
    for (int i = threadIdx.x; i < NG * 7; i += blockDim.x) acc[i] = 0.f;
    __syncthreads();
    int tid = blockIdx.x * blockDim.x + threadIdx.x;
    int stride = gridDim.x * blockDim.x;
    for (int e = tid; e < E; e += stride) {
        float d0 = disp[e*3], d1 = disp[e*3+1], d2 = disp[e*3+2];
        float c = -2.f * edge_w[e];
        int g0 = batch[edge_index[e]], g1 = batch[edge_index[E + e]];
        float v[6] = {c*d0*d0, c*d0*d1, c*d0*d2, c*d1*d1, c*d1*d2, c*d2*d2};
#pragma unroll
        for (int k = 0; k < 6; ++k) {
            lds_add(&acc[g0*7+k], v[k]);
            lds_add(&acc[g1*7+k], v[k]);
        }
    }
    __syncthreads();
    for (int i = threadIdx.x; i < NG * 9; i += blockDim.x) {
        int g = i / 9, ij = i % 9, r = ij / 3, cc = ij % 3;
        int lo = r < cc ? r : cc, hi = r < cc ? cc : r;
        int comp = (lo == 0) ? hi : ((lo == 1) ? 2 + hi : 5);
        __hip_atomic_fetch_add(&out[i], acc[g*7+comp], __ATOMIC_RELAXED, __HIP_MEMORY_SCOPE_AGENT);
    }
}

extern "C" void kernel_launch(void* const* d_in, const int* in_sizes, int n_in,
                              void* d_out, int out_size, void* d_ws, size_t ws_size,
                              hipStream_t stream) {
    const float* disp       = (const float*)d_in[0];
    const float* edge_w     = (const float*)d_in[1];
    const int*   edge_index = (const int*)d_in[2];
    const int*   batch      = (const int*)d_in[3];
    float*       out        = (float*)d_out;
    const int E = in_sizes[1];

    const size_t need = (size_t)(MFMA_BLOCKS + RED1_BLOCKS) * NPART * sizeof(float);

    if (ws_size >= need) {
        float* pm = (float*)d_ws;                         // [MFMA_BLOCKS][NPART]
        float* p2 = pm + (size_t)MFMA_BLOCKS * NPART;     // [RED1_BLOCKS][NPART]

        virial_mfma<<<MFMA_BLOCKS, 256, 0, stream>>>(disp, edge_w, edge_index, batch, pm, E);
        reduce1_kernel<<<RED1_BLOCKS, NPART, 0, stream>>>(pm, p2, MFMA_BLOCKS);
        reduce2_kernel<<<1, NPART, 0, stream>>>(p2, out);
    } else {
        zero_out_kernel<<<1, 256, 0, stream>>>(out, NG * 9);
        virial_atomic<<<2048, 256, 0, stream>>>(disp, edge_w, edge_index, batch, out, E);
    }
}

// Round 16
// 44.743 us; speedup vs baseline: 4.1666x; 1.1994x over previous
//
#include <hip/hip_runtime.h>

// R16: 3-stage pipelined loads on the R10-verified body (absmax 4, 44.2us).
// R15 post-mortem: R10/R15 both issue batch[s] in the SAME iteration as the
// edge_index load of s -> per-iteration vmcnt stall on the idx->gather hop.
// R16 decouples it: per iteration (1) gathers for grp+gs use idx loaded one
// iteration ago; (2) streaming loads (w,disp,idx) for grp+2gs; (3) compute
// grp with gather results issued one iteration ago. M/Dt/MFMA body unchanged.

#define NG 64
#define NCOMP 6
#define NPART (NG * NCOMP)      // 384
#define RED1_BLOCKS 64
#define MFMA_BLOCKS 768         // 3 blocks/CU (LDS-capped)
#define WPB 4
#define MROW 72                 // 64 + 8 pad ushorts; 144B rows (16B-aligned)
#define DROW 72

typedef unsigned short u16_t;
typedef unsigned int   u32_t;
typedef __attribute__((ext_vector_type(8))) short short8;
typedef __attribute__((ext_vector_type(4))) float f32x4;

__device__ __forceinline__ u16_t f2bf(float f) {
    union { float f; u32_t u; } v; v.f = f;
    u32_t r = v.u + 0x7FFFu + ((v.u >> 16) & 1u);
    return (u16_t)(r >> 16);
}

__device__ __forceinline__ void lds_add(float* p, float v) {
    __hip_atomic_fetch_add(p, v, __ATOMIC_RELAXED, __HIP_MEMORY_SCOPE_WORKGROUP);
}

// ---------------- MFMA main kernel ----------------
__global__ __launch_bounds__(256) void virial_mfma(
    const float* __restrict__ disp, const float* __restrict__ edge_w,
    const int* __restrict__ edge_index, const int* __restrict__ batch,
    float* __restrict__ partials, int E)
{
    __shared__ u16_t Msh[WPB][NG * MROW];   // 36864 B
    __shared__ u16_t Dsh[WPB][16 * DROW];   //  9216 B (rows 6..15 stay zero;
                                            //  reused as per-wave f32 stage)
    const int lane = threadIdx.x & 63;
    const int wave = threadIdx.x >> 6;
    u16_t* Mw = Msh[wave];
    u16_t* Dw = Dsh[wave];

    {   // zero per-wave M and Dt (same-wave DS ops are in order; no barrier)
        u32_t* p = (u32_t*)Mw;
        for (int i = lane; i < NG * MROW / 2; i += 64) p[i] = 0u;
        u32_t* q = (u32_t*)Dw;
        for (int i = lane; i < 16 * DROW / 2; i += 64) q[i] = 0u;
    }

    f32x4 acc0 = {0,0,0,0}, acc1 = {0,0,0,0}, acc2 = {0,0,0,0}, acc3 = {0,0,0,0};
    const int ngroups = (E + 63) >> 6;
    const int gstride = (int)gridDim.x * WPB;
    const int c_l = lane & 15;
    const int k4  = lane >> 4;
    int pg0 = 0, pg1 = 0;

    int grp = (int)blockIdx.x * WPB + wave;

    // ---- pipeline registers ----
    // A-stage: streaming data for group grp+gs (w,x,y,z and idx s,t)
    // C-stage: w,x,y,z for current group; g0f,g1f = gather results in flight
    float wA = 0.f, xA = 0.f, yA = 0.f, zA = 0.f;
    int   sA = 0, tA = 0;
    float wC = 0.f, xC = 0.f, yC = 0.f, zC = 0.f;
    int   g0f = 0, g1f = 0;

    if (grp < ngroups) {
        // prologue: stream group grp, gather immediately (one cold stall)
        {
            int e  = grp * 64 + lane;
            int ec = e < E ? e : E - 1;
            wC = (e < E) ? edge_w[ec] : 0.f;
            xC = disp[ec * 3 + 0];
            yC = disp[ec * 3 + 1];
            zC = disp[ec * 3 + 2];
            int s0 = edge_index[ec];
            int t0 = edge_index[E + ec];
            g0f = batch[s0];
            g1f = batch[t0];
        }
        // stream group grp+gs into A
        {
            int g2 = grp + gstride;
            int e  = g2 * 64 + lane;
            int ec = e < E ? e : E - 1;
            bool ok = (g2 < ngroups) && (e < E);
            wA = ok ? edge_w[ec] : 0.f;
            xA = disp[ec * 3 + 0];
            yA = disp[ec * 3 + 1];
            zA = disp[ec * 3 + 2];
            sA = edge_index[ec];
            tA = edge_index[E + ec];
        }
    }

    while (grp < ngroups) {
        const int nxt1 = grp + gstride;
        const int nxt2 = grp + 2 * gstride;

        // (1) gathers for nxt1 — sA/tA loaded one iteration ago
        int g0n = 0, g1n = 0;
        if (nxt1 < ngroups) {
            g0n = batch[sA];
            g1n = batch[tA];
        }

        // (2) streaming loads for nxt2 — fresh regs, consumed next iterations
        float wN = 0.f, xN = 0.f, yN = 0.f, zN = 0.f;
        int   sN = 0, tN = 0;
        if (nxt2 < ngroups) {
            int e  = nxt2 * 64 + lane;
            int ec = e < E ? e : E - 1;
            wN = (e < E) ? edge_w[ec] : 0.f;
            xN = disp[ec * 3 + 0];
            yN = disp[ec * 3 + 1];
            zN = disp[ec * 3 + 2];
            sN = edge_index[ec];
            tN = edge_index[E + ec];
        }

        // (3) compute current group — g0f/g1f issued one iteration ago
        {
            const int g0 = g0f, g1 = g1f;
            // --- R10-verified body ---
            Mw[pg0 * MROW + lane] = 0;
            Mw[pg1 * MROW + lane] = 0;
            Mw[g0 * MROW + lane] = 0x3F80u;                          // 1.0
            Mw[g1 * MROW + lane] = (g1 == g0) ? 0x4000u : 0x3F80u;   // 2.0 / 1.0
            pg0 = g0; pg1 = g1;

            float cw = -2.f * wC;
            Dw[0 * DROW + lane] = f2bf(cw * xC * xC);
            Dw[1 * DROW + lane] = f2bf(cw * xC * yC);
            Dw[2 * DROW + lane] = f2bf(cw * xC * zC);
            Dw[3 * DROW + lane] = f2bf(cw * yC * yC);
            Dw[4 * DROW + lane] = f2bf(cw * yC * zC);
            Dw[5 * DROW + lane] = f2bf(cw * zC * zC);

#pragma unroll
            for (int half = 0; half < 2; ++half) {
                const int kb = half * 32 + k4 * 8;
                short8 bf = *(const short8*)&Dw[c_l * DROW + kb];
                short8 a0 = *(const short8*)&Mw[( 0 + c_l) * MROW + kb];
                short8 a1 = *(const short8*)&Mw[(16 + c_l) * MROW + kb];
                short8 a2 = *(const short8*)&Mw[(32 + c_l) * MROW + kb];
                short8 a3 = *(const short8*)&Mw[(48 + c_l) * MROW + kb];
                acc0 = __builtin_amdgcn_mfma_f32_16x16x32_bf16(a0, bf, acc0, 0, 0, 0);
                acc1 = __builtin_amdgcn_mfma_f32_16x16x32_bf16(a1, bf, acc1, 0, 0, 0);
                acc2 = __builtin_amdgcn_mfma_f32_16x16x32_bf16(a2, bf, acc2, 0, 0, 0);
                acc3 = __builtin_amdgcn_mfma_f32_16x16x32_bf16(a3, bf, acc3, 0, 0, 0);
            }
        }

        // (4) shift pipeline
        wC = wA; xC = xA; yC = yA; zC = zA;
        wA = wN; xA = xN; yA = yN; zA = zN;
        sA = sN; tA = tN;
        g0f = g0n; g1f = g1n;

        grp = nxt1;
    }

    // C/D layout: col=lane&15, row=(lane>>4)*4+reg (m89-verified)
    float* Ow = (float*)Dw;   // Dt dead; 2304 B >= 1536 B needed
    if (c_l < NCOMP) {
#pragma unroll
        for (int r = 0; r < 4; ++r) {
            Ow[( 0 + k4 * 4 + r) * NCOMP + c_l] = acc0[r];
            Ow[(16 + k4 * 4 + r) * NCOMP + c_l] = acc1[r];
            Ow[(32 + k4 * 4 + r) * NCOMP + c_l] = acc2[r];
            Ow[(48 + k4 * 4 + r) * NCOMP + c_l] = acc3[r];
        }
    }
    __syncthreads();
    for (int i = threadIdx.x; i < NPART; i += blockDim.x) {
        float s = ((const float*)Dsh[0])[i] + ((const float*)Dsh[1])[i]
                + ((const float*)Dsh[2])[i] + ((const float*)Dsh[3])[i];
        partials[(size_t)blockIdx.x * NPART + i] = s;
    }
}

// ---------------- reductions (atomic-free) ----------------
__global__ __launch_bounds__(NPART) void reduce1_kernel(
    const float* __restrict__ partials, float* __restrict__ partials2, int nblk)
{
    int i = threadIdx.x, j = blockIdx.x;
    float s = 0.f;
    for (int b = j; b < nblk; b += RED1_BLOCKS)
        s += partials[(size_t)b * NPART + i];
    partials2[(size_t)j * NPART + i] = s;
}

__global__ __launch_bounds__(NPART) void reduce2_kernel(
    const float* __restrict__ partials2, float* __restrict__ dst)  // dst: 64*9
{
    int i = threadIdx.x;
    float s = 0.f;
#pragma unroll
    for (int j = 0; j < RED1_BLOCKS; ++j)
        s += partials2[(size_t)j * NPART + i];
    int g = i / NCOMP, c = i % NCOMP;
    int r   = (c < 3) ? 0 : ((c < 5) ? 1 : 2);
    int col = (c < 3) ? c : ((c < 5) ? c - 2 : 2);
    dst[g * 9 + r * 3 + col] = s;
    if (r != col) dst[g * 9 + col * 3 + r] = s;
}

// ---------------- fallback (tiny ws): LDS-atomic path ----------------
__global__ void zero_out_kernel(float* __restrict__ out, int n) {
    int i = blockIdx.x * blockDim.x + threadIdx.x;
    if (i < n) out[i] = 0.f;
}

__global__ __launch_bounds__(256) void virial_atomic(
    const float* __restrict__ disp, const float* __restrict__ edge_w,
    const int* __restrict__ edge_index, const int* __restrict__ batch,
    float* __restrict__ out, int E)
{
    __shared__ float acc[NG * 7];
    for (int i = threadIdx.x; i < NG * 7; i += blockDim.x) acc[i] = 0.f;
    __syncthreads();
    int tid = blockIdx.x * blockDim.x + threadIdx.x;
    int stride = gridDim.x * blockDim.x;
    for (int e = tid; e < E; e += stride) {
        float d0 = disp[e*3], d1 = disp[e*3+1], d2 = disp[e*3+2];
        float c = -2.f * edge_w[e];
        int g0 = batch[edge_index[e]], g1 = batch[edge_index[E + e]];
        float v[6] = {c*d0*d0, c*d0*d1, c*d0*d2, c*d1*d1, c*d1*d2, c*d2*d2};
#pragma unroll
        for (int k = 0; k < 6; ++k) {
            lds_add(&acc[g0*7+k], v[k]);
            lds_add(&acc[g1*7+k], v[k]);
        }
    }
    __syncthreads();
    for (int i = threadIdx.x; i < NG * 9; i += blockDim.x) {
        int g = i / 9, ij = i % 9, r = ij / 3, cc = ij % 3;
        int lo = r < cc ? r : cc, hi = r < cc ? cc : r;
        int comp = (lo == 0) ? hi : ((lo == 1) ? 2 + hi : 5);
        __hip_atomic_fetch_add(&out[i], acc[g*7+comp], __ATOMIC_RELAXED, __HIP_MEMORY_SCOPE_AGENT);
    }
}

extern "C" void kernel_launch(void* const* d_in, const int* in_sizes, int n_in,
                              void* d_out, int out_size, void* d_ws, size_t ws_size,
                              hipStream_t stream) {
    const float* disp       = (const float*)d_in[0];
    const float* edge_w     = (const float*)d_in[1];
    const int*   edge_index = (const int*)d_in[2];
    const int*   batch      = (const int*)d_in[3];
    float*       out        = (float*)d_out;
    const int E = in_sizes[1];

    const size_t need = (size_t)(MFMA_BLOCKS + RED1_BLOCKS) * NPART * sizeof(float);

    if (ws_size >= need) {
        float* pm = (float*)d_ws;                         // [MFMA_BLOCKS][NPART]
        float* p2 = pm + (size_t)MFMA_BLOCKS * NPART;     // [RED1_BLOCKS][NPART]

        virial_mfma<<<MFMA_BLOCKS, 256, 0, stream>>>(disp, edge_w, edge_index, batch, pm, E);
        reduce1_kernel<<<RED1_BLOCKS, NPART, 0, stream>>>(pm, p2, MFMA_BLOCKS);
        reduce2_kernel<<<1, NPART, 0, stream>>>(p2, out);
    } else {
        zero_out_kernel<<<1, 256, 0, stream>>>(out, NG * 9);
        virial_atomic<<<2048, 256, 0, stream>>>(disp, edge_w, edge_index, batch, out, E);
    }
}